// Round 16
// baseline (1686.832 us; speedup 1.0000x reference)
//
#include <hip/hip_runtime.h>
#include <hip/hip_bf16.h>
#include <math.h>

#define H_DIM 2048
#define N_ST 8
#define B_SZ 4
#define L_SEQ 4096
#define DMODEL 1024
#define DCONV 4
#define CL 128
#define NC (L_SEQ / CL)   // 32

typedef __bf16 bf16x8 __attribute__((ext_vector_type(8)));
typedef __bf16 bf16x4 __attribute__((ext_vector_type(4)));
typedef float f32x4 __attribute__((ext_vector_type(4)));

typedef const unsigned int __attribute__((address_space(1)))* gptr_t;
typedef unsigned int __attribute__((address_space(3)))* lptr_t;

__device__ __forceinline__ void gl_lds16(const __bf16* g, __bf16* l) {
    __builtin_amdgcn_global_load_lds((gptr_t)g, (lptr_t)l, 16, 0, 0);
}

// -------- workspace layout (floats), total 36,798,464 f = 147.2 MB --------
#define WS_XZ     0
#define WS_COEF   16777216
#define WS_STATES 16875520
#define WS_HF     17924096   // fused hid bf16 [4096][3072]; later yTh bf16 [4096][2048]
#define WS_WIF    24215552   // fused W_in bf16 [4096][3072]
#define WS_WOH    30507008   // W_out hi plane bf16 [1024][2048]
#define WS_WOL    31555584   // W_out lo plane
#define WS_YTL    32604160   // yTl bf16 [4096][2048]

// ============ split f32 -> bf16 hi/lo planes (for W_out) ============
__global__ __launch_bounds__(256) void cvt_split4(const float* __restrict__ s,
                                                  __bf16* __restrict__ h,
                                                  __bf16* __restrict__ l, int n4) {
    int i = blockIdx.x * 256 + threadIdx.x;
    if (i >= n4) return;
    float4 v = ((const float4*)s)[i];
    float vv[4] = {v.x, v.y, v.z, v.w};
    bf16x4 hv, lv;
#pragma unroll
    for (int j = 0; j < 4; ++j) {
        __bf16 hb = (__bf16)vv[j];
        hv[j] = hb;
        lv[j] = (__bf16)(vv[j] - (float)hb);
    }
    *(bf16x4*)&h[(size_t)i * 4] = hv;
    *(bf16x4*)&l[(size_t)i * 4] = lv;
}

// ============ fuse f32 [R][1024] -> bf16 [R][3072] triplet octs ============
template <int BSIDE>
__global__ __launch_bounds__(256) void cvt_fuse(const float* __restrict__ s,
                                                __bf16* __restrict__ d, int nOct) {
    int i = blockIdx.x * 256 + threadIdx.x;
    if (i >= nOct) return;
    int row = i >> 7, ko = i & 127;
    const float* p = s + (size_t)row * 1024 + ko * 8;
    float4 v0 = *(const float4*)p;
    float4 v1 = *(const float4*)(p + 4);
    float vv[8] = {v0.x, v0.y, v0.z, v0.w, v1.x, v1.y, v1.z, v1.w};
    bf16x8 hv, lv;
#pragma unroll
    for (int j = 0; j < 8; ++j) {
        __bf16 hb = (__bf16)vv[j];
        hv[j] = hb;
        lv[j] = (__bf16)(vv[j] - (float)hb);
    }
    __bf16* o = d + (size_t)row * 3072 + ko * 24;
    if (BSIDE) {
        *(bf16x8*)(o) = hv; *(bf16x8*)(o + 8) = lv; *(bf16x8*)(o + 16) = hv;
    } else {
        *(bf16x8*)(o) = hv; *(bf16x8*)(o + 8) = hv; *(bf16x8*)(o + 16) = lv;
    }
}

// ============ coefficient precompute ============
__global__ void coef_kernel(const float* __restrict__ log_dt,
                            const float* __restrict__ log_A_real,
                            const float* __restrict__ A_imag,
                            const float* __restrict__ C_re,
                            const float* __restrict__ C_im,
                            float* __restrict__ coef) {
    int i = blockIdx.x * blockDim.x + threadIdx.x;
    if (i >= H_DIM * N_ST) return;
    int h = i >> 3;
    float dt = expf(log_dt[h]);
    float Ar = -expf(log_A_real[i]);
    float Ai = A_imag[i];
    float er = expf(dt * Ar);
    float ang = dt * Ai;
    float wr = er * cosf(ang);
    float wi = er * sinf(ang);
    float den = Ar * Ar + Ai * Ai;
    float qr = ((wr - 1.f) * Ar + wi * Ai) / den;
    float qi = (wi * Ar - (wr - 1.f) * Ai) / den;
    float Cr = C_re[i], Ci = C_im[i];
    float Ctr = Cr * qr - Ci * qi;
    float Cti = Cr * qi + Ci * qr;
    float eCL = expf((float)CL * dt * Ar);
    float aCL = (float)CL * dt * Ai;
    float pr = eCL * cosf(aCL);
    float pi = eCL * sinf(aCL);
    const int HN = H_DIM * N_ST;
    coef[i]          = wr;
    coef[HN + i]     = wi;
    coef[2 * HN + i] = Ctr;
    coef[3 * HN + i] = Cti;
    coef[4 * HN + i] = pr;
    coef[5 * HN + i] = pi;
}

// ============ 128x128 fused single-plane bf16 GEMM — 4-phase/ks-split, 64 KB LDS ============
// Same cadence as the round-11 winner, single operand plane -> 2 blocks/CU co-resident
// (cross-block overlap hides barrier drains). 4 waves (2x2), wave tile 64x64, BK=64.
// Stage piece = 2 gl_lds/thread; gates vmcnt(4) (oldest 4 = piece needed next phase).
__global__ __launch_bounds__(256, 2) void gemm_g128(const __bf16* __restrict__ A,
                                                    const __bf16* __restrict__ B,
                                                    float* __restrict__ C,
                                                    int K, int ldc) {
    __shared__ __bf16 sA[2][2][4096], sB[2][2][4096];   // [par][ks][koct 0..3][row 0..127][8]
    const int tid = threadIdx.x;
    const int lane = tid & 63;
    const int wid = tid >> 6;
    const int wrw = wid >> 1, wcw = wid & 1;
    const int bm = blockIdx.y, bn = blockIdx.x;

    f32x4 acc[4][4];
#pragma unroll
    for (int m = 0; m < 4; ++m)
#pragma unroll
        for (int n = 0; n < 4; ++n) acc[m][n] = (f32x4){0.f, 0.f, 0.f, 0.f};

    const int kb = lane >> 4, rr = lane & 15;

    const int o0 = tid, o1 = 256 + tid;
    const int ko0 = o0 >> 7, rw0 = o0 & 127;
    const int ko1 = o1 >> 7, rw1 = o1 & 127;
    const size_t gA0 = (size_t)(bm * 128 + rw0) * K;
    const size_t gA1 = (size_t)(bm * 128 + rw1) * K;
    const size_t gB0 = (size_t)(bn * 128 + rw0) * K;
    const size_t gB1 = (size_t)(bn * 128 + rw1) * K;
    const int d0 = ko0 * 1024 + rw0 * 8;
    const int d1 = ko1 * 1024 + rw1 * 8;

    auto stA = [&](int t, int ks) {
        const int par = t & 1;
        const size_t go = (size_t)t * 64 + ks * 32;
        gl_lds16(A + gA0 + go + ko0 * 8, &sA[par][ks][d0]);
        gl_lds16(A + gA1 + go + ko1 * 8, &sA[par][ks][d1]);
    };
    auto stB = [&](int t, int ks) {
        const int par = t & 1;
        const size_t go = (size_t)t * 64 + ks * 32;
        gl_lds16(B + gB0 + go + ko0 * 8, &sB[par][ks][d0]);
        gl_lds16(B + gB1 + go + ko1 * 8, &sB[par][ks][d1]);
    };

    const int nt = K >> 6;   // BK=64
    stA(0, 0); stB(0, 0); stA(0, 1); stB(0, 1);
    asm volatile("s_waitcnt vmcnt(0)" ::: "memory");
    __builtin_amdgcn_s_barrier();
    __builtin_amdgcn_sched_barrier(0);

    bf16x8 fA[4], fB[4];

#pragma unroll 1
    for (int t = 0; t < nt; ++t) {
        const int par = t & 1;
        const bool pf = (t + 1 < nt);

        // ===== phase 0 (ks=0): read all frags, stage A(t+1,ks0), MFMA m0,m1 =====
        {
#pragma unroll
            for (int n = 0; n < 4; ++n)
                fB[n] = *(const bf16x8*)&sB[par][0][kb * 1024 + (wcw * 64 + n * 16 + rr) * 8];
#pragma unroll
            for (int m = 0; m < 4; ++m)
                fA[m] = *(const bf16x8*)&sA[par][0][kb * 1024 + (wrw * 64 + m * 16 + rr) * 8];
            if (pf) stA(t + 1, 0);
            __builtin_amdgcn_s_barrier();
            asm volatile("s_waitcnt lgkmcnt(0)" ::: "memory");
            __builtin_amdgcn_sched_barrier(0);
            __builtin_amdgcn_s_setprio(1);
#pragma unroll
            for (int m = 0; m < 2; ++m)
#pragma unroll
                for (int n = 0; n < 4; ++n)
                    acc[m][n] = __builtin_amdgcn_mfma_f32_16x16x32_bf16(fA[m], fB[n], acc[m][n], 0, 0, 0);
            __builtin_amdgcn_s_setprio(0);
            __builtin_amdgcn_s_barrier();
            __builtin_amdgcn_sched_barrier(0);
        }
        // ===== phase 1 (ks=0): stage B(t+1,ks0), MFMA m2,m3, gate =====
        {
            if (pf) stB(t + 1, 0);
            __builtin_amdgcn_s_barrier();
            __builtin_amdgcn_sched_barrier(0);
            __builtin_amdgcn_s_setprio(1);
#pragma unroll
            for (int m = 2; m < 4; ++m)
#pragma unroll
                for (int n = 0; n < 4; ++n)
                    acc[m][n] = __builtin_amdgcn_mfma_f32_16x16x32_bf16(fA[m], fB[n], acc[m][n], 0, 0, 0);
            __builtin_amdgcn_s_setprio(0);
            if (pf) asm volatile("s_waitcnt vmcnt(4)" ::: "memory");
            else    asm volatile("s_waitcnt vmcnt(0)" ::: "memory");
            __builtin_amdgcn_s_barrier();
            __builtin_amdgcn_sched_barrier(0);
        }
        // ===== phase 2 (ks=1): read all frags, stage A(t+1,ks1), MFMA m0,m1 =====
        {
#pragma unroll
            for (int n = 0; n < 4; ++n)
                fB[n] = *(const bf16x8*)&sB[par][1][kb * 1024 + (wcw * 64 + n * 16 + rr) * 8];
#pragma unroll
            for (int m = 0; m < 4; ++m)
                fA[m] = *(const bf16x8*)&sA[par][1][kb * 1024 + (wrw * 64 + m * 16 + rr) * 8];
            if (pf) stA(t + 1, 1);
            __builtin_amdgcn_s_barrier();
            asm volatile("s_waitcnt lgkmcnt(0)" ::: "memory");
            __builtin_amdgcn_sched_barrier(0);
            __builtin_amdgcn_s_setprio(1);
#pragma unroll
            for (int m = 0; m < 2; ++m)
#pragma unroll
                for (int n = 0; n < 4; ++n)
                    acc[m][n] = __builtin_amdgcn_mfma_f32_16x16x32_bf16(fA[m], fB[n], acc[m][n], 0, 0, 0);
            __builtin_amdgcn_s_setprio(0);
            __builtin_amdgcn_s_barrier();
            __builtin_amdgcn_sched_barrier(0);
        }
        // ===== phase 3 (ks=1): stage B(t+1,ks1), MFMA m2,m3, gate =====
        {
            if (pf) stB(t + 1, 1);
            __builtin_amdgcn_s_barrier();
            __builtin_amdgcn_sched_barrier(0);
            __builtin_amdgcn_s_setprio(1);
#pragma unroll
            for (int m = 2; m < 4; ++m)
#pragma unroll
                for (int n = 0; n < 4; ++n)
                    acc[m][n] = __builtin_amdgcn_mfma_f32_16x16x32_bf16(fA[m], fB[n], acc[m][n], 0, 0, 0);
            __builtin_amdgcn_s_setprio(0);
            if (pf) asm volatile("s_waitcnt vmcnt(4)" ::: "memory");
            else    asm volatile("s_waitcnt vmcnt(0)" ::: "memory");
            __builtin_amdgcn_s_barrier();
            __builtin_amdgcn_sched_barrier(0);
        }
    }

    const int rq = lane >> 4;
#pragma unroll
    for (int m = 0; m < 4; ++m)
#pragma unroll
        for (int n = 0; n < 4; ++n) {
            int col = bn * 128 + wcw * 64 + n * 16 + rr;
            int row0 = bm * 128 + wrw * 64 + m * 16 + rq * 4;
#pragma unroll
            for (int j = 0; j < 4; ++j)
                C[(size_t)(row0 + j) * ldc + col] = acc[m][n][j];
        }
}

// ============ 128x128 split-plane out-GEMM — 512 threads / 8 waves (round-15 WIN) ============
__global__ __launch_bounds__(512, 1) void gemm_s128w(const __bf16* __restrict__ Ah,
                                                     const __bf16* __restrict__ Al,
                                                     const __bf16* __restrict__ Bh,
                                                     const __bf16* __restrict__ Bl,
                                                     float* __restrict__ C,
                                                     int K, int ldc) {
    __shared__ __bf16 sAh[2][2][4096], sAl[2][2][4096];
    __shared__ __bf16 sBh[2][2][4096], sBl[2][2][4096];
    const int tid = threadIdx.x;
    const int lane = tid & 63;
    const int wid = tid >> 6;
    const int wrw = wid >> 2;
    const int wcw = wid & 3;
    const int bm = blockIdx.y, bn = blockIdx.x;

    f32x4 acc[4][2];
#pragma unroll
    for (int m = 0; m < 4; ++m)
#pragma unroll
        for (int n = 0; n < 2; ++n) acc[m][n] = (f32x4){0.f, 0.f, 0.f, 0.f};

    const int kb = lane >> 4, rr = lane & 15;

    const int kbs = tid >> 7, rw = tid & 127;
    const size_t gAr = (size_t)(bm * 128 + rw) * K;
    const size_t gBr = (size_t)(bn * 128 + rw) * K;
    const int dd = kbs * 1024 + rw * 8;

    auto stA = [&](int t, int ks) {
        const int par = t & 1;
        const size_t go = (size_t)t * 64 + ks * 32 + kbs * 8;
        gl_lds16(Ah + gAr + go, &sAh[par][ks][dd]);
        gl_lds16(Al + gAr + go, &sAl[par][ks][dd]);
    };
    auto stB = [&](int t, int ks) {
        const int par = t & 1;
        const size_t go = (size_t)t * 64 + ks * 32 + kbs * 8;
        gl_lds16(Bh + gBr + go, &sBh[par][ks][dd]);
        gl_lds16(Bl + gBr + go, &sBl[par][ks][dd]);
    };

    const int nt = K >> 6;   // BK=64
    stA(0, 0); stB(0, 0); stA(0, 1); stB(0, 1);
    asm volatile("s_waitcnt vmcnt(0)" ::: "memory");
    __builtin_amdgcn_s_barrier();
    __builtin_amdgcn_sched_barrier(0);

    bf16x8 fAh[4], fAl[4], fBh[2], fBl[2];

#pragma unroll 1
    for (int t = 0; t < nt; ++t) {
        const int par = t & 1;
        const bool pf = (t + 1 < nt);

        // ===== phase 0 (ks=0) =====
        {
#pragma unroll
            for (int n = 0; n < 2; ++n) {
                const int off = kb * 1024 + (wcw * 32 + n * 16 + rr) * 8;
                fBh[n] = *(const bf16x8*)&sBh[par][0][off];
                fBl[n] = *(const bf16x8*)&sBl[par][0][off];
            }
#pragma unroll
            for (int m = 0; m < 4; ++m) {
                const int off = kb * 1024 + (wrw * 64 + m * 16 + rr) * 8;
                fAh[m] = *(const bf16x8*)&sAh[par][0][off];
                fAl[m] = *(const bf16x8*)&sAl[par][0][off];
            }
            if (pf) stA(t + 1, 0);
            __builtin_amdgcn_s_barrier();
            asm volatile("s_waitcnt lgkmcnt(0)" ::: "memory");
            __builtin_amdgcn_sched_barrier(0);
            __builtin_amdgcn_s_setprio(1);
#pragma unroll
            for (int m = 0; m < 2; ++m)
#pragma unroll
                for (int n = 0; n < 2; ++n) {
                    acc[m][n] = __builtin_amdgcn_mfma_f32_16x16x32_bf16(fAh[m], fBh[n], acc[m][n], 0, 0, 0);
                    acc[m][n] = __builtin_amdgcn_mfma_f32_16x16x32_bf16(fAh[m], fBl[n], acc[m][n], 0, 0, 0);
                    acc[m][n] = __builtin_amdgcn_mfma_f32_16x16x32_bf16(fAl[m], fBh[n], acc[m][n], 0, 0, 0);
                }
            __builtin_amdgcn_s_setprio(0);
            __builtin_amdgcn_s_barrier();
            __builtin_amdgcn_sched_barrier(0);
        }
        // ===== phase 1 (ks=0) [gate] =====
        {
            if (pf) stB(t + 1, 0);
            __builtin_amdgcn_s_barrier();
            __builtin_amdgcn_sched_barrier(0);
            __builtin_amdgcn_s_setprio(1);
#pragma unroll
            for (int m = 2; m < 4; ++m)
#pragma unroll
                for (int n = 0; n < 2; ++n) {
                    acc[m][n] = __builtin_amdgcn_mfma_f32_16x16x32_bf16(fAh[m], fBh[n], acc[m][n], 0, 0, 0);
                    acc[m][n] = __builtin_amdgcn_mfma_f32_16x16x32_bf16(fAh[m], fBl[n], acc[m][n], 0, 0, 0);
                    acc[m][n] = __builtin_amdgcn_mfma_f32_16x16x32_bf16(fAl[m], fBh[n], acc[m][n], 0, 0, 0);
                }
            __builtin_amdgcn_s_setprio(0);
            if (pf) asm volatile("s_waitcnt vmcnt(4)" ::: "memory");
            else    asm volatile("s_waitcnt vmcnt(0)" ::: "memory");
            __builtin_amdgcn_s_barrier();
            __builtin_amdgcn_sched_barrier(0);
        }
        // ===== phase 2 (ks=1) =====
        {
#pragma unroll
            for (int n = 0; n < 2; ++n) {
                const int off = kb * 1024 + (wcw * 32 + n * 16 + rr) * 8;
                fBh[n] = *(const bf16x8*)&sBh[par][1][off];
                fBl[n] = *(const bf16x8*)&sBl[par][1][off];
            }
#pragma unroll
            for (int m = 0; m < 4; ++m) {
                const int off = kb * 1024 + (wrw * 64 + m * 16 + rr) * 8;
                fAh[m] = *(const bf16x8*)&sAh[par][1][off];
                fAl[m] = *(const bf16x8*)&sAl[par][1][off];
            }
            if (pf) stA(t + 1, 1);
            __builtin_amdgcn_s_barrier();
            asm volatile("s_waitcnt lgkmcnt(0)" ::: "memory");
            __builtin_amdgcn_sched_barrier(0);
            __builtin_amdgcn_s_setprio(1);
#pragma unroll
            for (int m = 0; m < 2; ++m)
#pragma unroll
                for (int n = 0; n < 2; ++n) {
                    acc[m][n] = __builtin_amdgcn_mfma_f32_16x16x32_bf16(fAh[m], fBh[n], acc[m][n], 0, 0, 0);
                    acc[m][n] = __builtin_amdgcn_mfma_f32_16x16x32_bf16(fAh[m], fBl[n], acc[m][n], 0, 0, 0);
                    acc[m][n] = __builtin_amdgcn_mfma_f32_16x16x32_bf16(fAl[m], fBh[n], acc[m][n], 0, 0, 0);
                }
            __builtin_amdgcn_s_setprio(0);
            __builtin_amdgcn_s_barrier();
            __builtin_amdgcn_sched_barrier(0);
        }
        // ===== phase 3 (ks=1) [gate] =====
        {
            if (pf) stB(t + 1, 1);
            __builtin_amdgcn_s_barrier();
            __builtin_amdgcn_sched_barrier(0);
            __builtin_amdgcn_s_setprio(1);
#pragma unroll
            for (int m = 2; m < 4; ++m)
#pragma unroll
                for (int n = 0; n < 2; ++n) {
                    acc[m][n] = __builtin_amdgcn_mfma_f32_16x16x32_bf16(fAh[m], fBh[n], acc[m][n], 0, 0, 0);
                    acc[m][n] = __builtin_amdgcn_mfma_f32_16x16x32_bf16(fAh[m], fBl[n], acc[m][n], 0, 0, 0);
                    acc[m][n] = __builtin_amdgcn_mfma_f32_16x16x32_bf16(fAl[m], fBh[n], acc[m][n], 0, 0, 0);
                }
            __builtin_amdgcn_s_setprio(0);
            if (pf) asm volatile("s_waitcnt vmcnt(4)" ::: "memory");
            else    asm volatile("s_waitcnt vmcnt(0)" ::: "memory");
            __builtin_amdgcn_s_barrier();
            __builtin_amdgcn_sched_barrier(0);
        }
    }

    const int rq = lane >> 4;
#pragma unroll
    for (int m = 0; m < 4; ++m)
#pragma unroll
        for (int n = 0; n < 2; ++n) {
            int col = bn * 128 + wcw * 32 + n * 16 + rr;
            int row0 = bm * 128 + wrw * 64 + m * 16 + rq * 4;
#pragma unroll
            for (int j = 0; j < 4; ++j)
                C[(size_t)(row0 + j) * ldc + col] = acc[m][n][j];
        }
}

// ============ scan phase 1: local chunk scans (fused conv+SiLU) ============
__global__ __launch_bounds__(256) void scan_phase1(const float* __restrict__ xz,
                                                   const float* __restrict__ coef,
                                                   const float* __restrict__ conv_w,
                                                   const float* __restrict__ conv_b,
                                                   float* __restrict__ states) {
    int t = blockIdx.x * 256 + threadIdx.x;   // t = h*NC + c
    int c = t & (NC - 1);
    int h = t >> 5;

    const int HN = H_DIM * N_ST;
    float wr[N_ST], wi[N_ST];
#pragma unroll
    for (int n = 0; n < N_ST; ++n) {
        wr[n] = coef[h * N_ST + n];
        wi[n] = coef[HN + h * N_ST + n];
    }
    float cw0 = conv_w[h * 4 + 0], cw1 = conv_w[h * 4 + 1];
    float cw2 = conv_w[h * 4 + 2], cw3 = conv_w[h * 4 + 3];
    float cb = conv_b[h];

    const float* xrow = xz + (size_t)h * L_SEQ + c * CL;
    float x3 = 0.f, x2 = 0.f, x1 = 0.f;
    if (c > 0) {
        float4 p = *(const float4*)(xrow - 4);
        x3 = p.y; x2 = p.z; x1 = p.w;
    }

    float sr[N_ST], si[N_ST];
#pragma unroll
    for (int n = 0; n < N_ST; ++n) { sr[n] = 0.f; si[n] = 0.f; }

    for (int j = 0; j < CL; j += 4) {
        float4 v = *(const float4*)(xrow + j);
        float xv[4] = {v.x, v.y, v.z, v.w};
#pragma unroll
        for (int k = 0; k < 4; ++k) {
            float u = cw0 * x3 + cw1 * x2 + cw2 * x1 + cw3 * xv[k] + cb;
            float xc = u / (1.f + __expf(-u));
            x3 = x2; x2 = x1; x1 = xv[k];
#pragma unroll
            for (int n = 0; n < N_ST; ++n) {
                float nr = wr[n] * sr[n] - wi[n] * si[n] + xc;
                float ni = wr[n] * si[n] + wi[n] * sr[n];
                sr[n] = nr; si[n] = ni;
            }
        }
    }
    float* st = states + (size_t)t * (N_ST * 2);
#pragma unroll
    for (int n = 0; n < N_ST; ++n) { st[2 * n] = sr[n]; st[2 * n + 1] = si[n]; }
}

// ============ scan phase 2: combine chunk states -> chunk init states ============
__global__ __launch_bounds__(256) void scan_phase2(const float* __restrict__ coef,
                                                   float* __restrict__ states) {
    int h = blockIdx.x * 256 + threadIdx.x;
    if (h >= H_DIM) return;
    const int HN = H_DIM * N_ST;
    float pr[N_ST], pi[N_ST];
#pragma unroll
    for (int n = 0; n < N_ST; ++n) {
        pr[n] = coef[4 * HN + h * N_ST + n];
        pi[n] = coef[5 * HN + h * N_ST + n];
    }
    float sr[N_ST], si[N_ST];
#pragma unroll
    for (int n = 0; n < N_ST; ++n) { sr[n] = 0.f; si[n] = 0.f; }
    float* base = states + (size_t)h * NC * (N_ST * 2);
    for (int c = 0; c < NC; ++c) {
        float* st = base + c * (N_ST * 2);
#pragma unroll
        for (int n = 0; n < N_ST; ++n) {
            float lr = st[2 * n], li = st[2 * n + 1];
            st[2 * n] = sr[n]; st[2 * n + 1] = si[n];
            float nr = pr[n] * sr[n] - pi[n] * si[n] + lr;
            float ni = pr[n] * si[n] + pi[n] * sr[n] + li;
            sr[n] = nr; si[n] = ni;
        }
    }
}

// ============ scan phase 3 + transpose + split fused ============
__global__ __launch_bounds__(256) void scan_phase3t(const float* __restrict__ xz,
                                                    const float* __restrict__ coef,
                                                    const float* __restrict__ conv_w,
                                                    const float* __restrict__ conv_b,
                                                    const float* __restrict__ Dvec,
                                                    const float* __restrict__ states,
                                                    __bf16* __restrict__ th,
                                                    __bf16* __restrict__ tl) {
    const int lane = threadIdx.x & 63;
    const int wv = threadIdx.x >> 6;             // 0..3
    const int c = blockIdx.x * 4 + wv;           // chunk 0..31
    const int h = blockIdx.y * 64 + lane;        // 0..2047
    const int t = h * NC + c;

    const int HN = H_DIM * N_ST;
    float wr[N_ST], wi[N_ST], Ctr[N_ST], Cti[N_ST];
#pragma unroll
    for (int n = 0; n < N_ST; ++n) {
        wr[n]  = coef[h * N_ST + n];
        wi[n]  = coef[HN + h * N_ST + n];
        Ctr[n] = coef[2 * HN + h * N_ST + n];
        Cti[n] = coef[3 * HN + h * N_ST + n];
    }
    float cw0 = conv_w[h * 4 + 0], cw1 = conv_w[h * 4 + 1];
    float cw2 = conv_w[h * 4 + 2], cw3 = conv_w[h * 4 + 3];
    float cb = conv_b[h];
    float Dh = Dvec[h];

    const float* xrow = xz + (size_t)h * L_SEQ + c * CL;
    const float* zrow = xz + (size_t)(H_DIM + h) * L_SEQ + c * CL;

    float x3 = 0.f, x2 = 0.f, x1 = 0.f;
    if (c > 0) {
        float4 p = *(const float4*)(xrow - 4);
        x3 = p.y; x2 = p.z; x1 = p.w;
    }

    const float* st = states + (size_t)t * (N_ST * 2);
    float sr[N_ST], si[N_ST];
#pragma unroll
    for (int n = 0; n < N_ST; ++n) { sr[n] = st[2 * n]; si[n] = st[2 * n + 1]; }

    __bf16* thp = th + (size_t)(c * CL) * H_DIM + h;
    __bf16* tlp = tl + (size_t)(c * CL) * H_DIM + h;

    for (int j = 0; j < CL; j += 4) {
        float4 v = *(const float4*)(xrow + j);
        float4 zv = *(const float4*)(zrow + j);
        float xv[4] = {v.x, v.y, v.z, v.w};
        float zz[4] = {zv.x, zv.y, zv.z, zv.w};
#pragma unroll
        for (int k = 0; k < 4; ++k) {
            float u = cw0 * x3 + cw1 * x2 + cw2 * x1 + cw3 * xv[k] + cb;
            float xc = u / (1.f + __expf(-u));
            x3 = x2; x2 = x1; x1 = xv[k];
            float accy = 0.f;
#pragma unroll
            for (int n = 0; n < N_ST; ++n) {
                float nr = wr[n] * sr[n] - wi[n] * si[n] + xc;
                float ni = wr[n] * si[n] + wi[n] * sr[n];
                sr[n] = nr; si[n] = ni;
                accy += Ctr[n] * nr - Cti[n] * ni;
            }
            float yv = 2.f * accy + Dh * xc;
            float g = zz[k] / (1.f + __expf(-zz[k]));
            float val = yv * g;
            __bf16 hb = (__bf16)val;
            __bf16 lb = (__bf16)(val - (float)hb);
            thp[(size_t)(j + k) * H_DIM] = hb;
            tlp[(size_t)(j + k) * H_DIM] = lb;
        }
    }
}

extern "C" void kernel_launch(void* const* d_in, const int* in_sizes, int n_in,
                              void* d_out, int out_size, void* d_ws, size_t ws_size,
                              hipStream_t stream) {
    const float* hid        = (const float*)d_in[0];
    const float* W_in       = (const float*)d_in[1];
    const float* conv_w     = (const float*)d_in[2];
    const float* conv_b     = (const float*)d_in[3];
    const float* log_dt     = (const float*)d_in[4];
    const float* log_A_real = (const float*)d_in[5];
    const float* A_imag     = (const float*)d_in[6];
    const float* C_re       = (const float*)d_in[7];
    const float* C_im       = (const float*)d_in[8];
    const float* Dv         = (const float*)d_in[9];
    const float* W_out      = (const float*)d_in[10];
    float* out = (float*)d_out;
    float* ws  = (float*)d_ws;

    float* xz      = ws + WS_XZ;
    float* coef    = ws + WS_COEF;
    float* states  = ws + WS_STATES;
    __bf16* Hf     = (__bf16*)(ws + WS_HF);
    __bf16* WiF    = (__bf16*)(ws + WS_WIF);
    __bf16* Woh    = (__bf16*)(ws + WS_WOH);
    __bf16* Wol    = (__bf16*)(ws + WS_WOL);
    __bf16* yTh    = (__bf16*)(ws + WS_HF);    // overlays Hf (dead at phase3t time)
    __bf16* yTl    = (__bf16*)(ws + WS_YTL);

    coef_kernel<<<(H_DIM * N_ST + 255) / 256, 256, 0, stream>>>(
        log_dt, log_A_real, A_imag, C_re, C_im, coef);

    const int wOct = 2 * H_DIM * DMODEL / 8;   // 524288
    cvt_fuse<0><<<(wOct + 255) / 256, 256, 0, stream>>>(W_in, WiF, wOct);
    cvt_split4<<<(DMODEL * H_DIM / 4 + 255) / 256, 256, 0, stream>>>(W_out, Woh, Wol, DMODEL * H_DIM / 4);

    const int nscan = H_DIM * NC;              // 65536
    const int hOct = L_SEQ * DMODEL / 8;       // 524288
    dim3 gIn(L_SEQ / 128, 2 * H_DIM / 128);    // (32,32) = 1024 blocks, 2/CU co-resident
    dim3 gOut(DMODEL / 128, L_SEQ / 128);      // (8,32)  = 256 blocks
    dim3 gP3(NC / 4, H_DIM / 64);              // (8,32)  = 256 blocks

    for (int b = 0; b < B_SZ; ++b) {
        const float* hid_b = hid + (size_t)b * L_SEQ * DMODEL;
        float* out_b = out + (size_t)b * L_SEQ * DMODEL;

        cvt_fuse<1><<<(hOct + 255) / 256, 256, 0, stream>>>(hid_b, Hf, hOct);
        gemm_g128<<<gIn, 256, 0, stream>>>(WiF, Hf, xz, 3 * DMODEL, L_SEQ);
        scan_phase1<<<nscan / 256, 256, 0, stream>>>(xz, coef, conv_w, conv_b, states);
        scan_phase2<<<(H_DIM + 255) / 256, 256, 0, stream>>>(coef, states);
        scan_phase3t<<<gP3, 256, 0, stream>>>(xz, coef, conv_w, conv_b, Dv, states, yTh, yTl);
        gemm_s128w<<<gOut, 512, 0, stream>>>(yTh, yTl, Woh, Wol, out_b, H_DIM, DMODEL);
    }
}

// Round 17
// 1399.203 us; speedup vs baseline: 1.2056x; 1.2056x over previous
//
#include <hip/hip_runtime.h>
#include <hip/hip_bf16.h>
#include <math.h>

#define H_DIM 2048
#define N_ST 8
#define B_SZ 4
#define L_SEQ 4096
#define DMODEL 1024
#define DCONV 4
#define CL 128
#define NC (L_SEQ / CL)   // 32

typedef __bf16 bf16x8 __attribute__((ext_vector_type(8)));
typedef __bf16 bf16x4 __attribute__((ext_vector_type(4)));
typedef float f32x4 __attribute__((ext_vector_type(4)));

typedef const unsigned int __attribute__((address_space(1)))* gptr_t;
typedef unsigned int __attribute__((address_space(3)))* lptr_t;

__device__ __forceinline__ void gl_lds16(const __bf16* g, __bf16* l) {
    __builtin_amdgcn_global_load_lds((gptr_t)g, (lptr_t)l, 16, 0, 0);
}

// -------- workspace layout (floats), total 36,798,464 f = 147.2 MB --------
#define WS_XZ     0
#define WS_COEF   16777216
#define WS_STATES 16875520
#define WS_HF     17924096   // fused hid bf16 [4096][3072]; later yTh bf16 [4096][2048]
#define WS_WIF    24215552   // fused W_in bf16 [4096][3072]
#define WS_WOH    30507008   // W_out hi plane bf16 [1024][2048]
#define WS_WOL    31555584   // W_out lo plane
#define WS_YTL    32604160   // yTl bf16 [4096][2048]

// ============ split f32 -> bf16 hi/lo planes (for W_out) ============
__global__ __launch_bounds__(256) void cvt_split4(const float* __restrict__ s,
                                                  __bf16* __restrict__ h,
                                                  __bf16* __restrict__ l, int n4) {
    int i = blockIdx.x * 256 + threadIdx.x;
    if (i >= n4) return;
    float4 v = ((const float4*)s)[i];
    float vv[4] = {v.x, v.y, v.z, v.w};
    bf16x4 hv, lv;
#pragma unroll
    for (int j = 0; j < 4; ++j) {
        __bf16 hb = (__bf16)vv[j];
        hv[j] = hb;
        lv[j] = (__bf16)(vv[j] - (float)hb);
    }
    *(bf16x4*)&h[(size_t)i * 4] = hv;
    *(bf16x4*)&l[(size_t)i * 4] = lv;
}

// ============ fuse f32 [R][1024] -> bf16 [R][3072] triplet octs ============
template <int BSIDE>
__global__ __launch_bounds__(256) void cvt_fuse(const float* __restrict__ s,
                                                __bf16* __restrict__ d, int nOct) {
    int i = blockIdx.x * 256 + threadIdx.x;
    if (i >= nOct) return;
    int row = i >> 7, ko = i & 127;
    const float* p = s + (size_t)row * 1024 + ko * 8;
    float4 v0 = *(const float4*)p;
    float4 v1 = *(const float4*)(p + 4);
    float vv[8] = {v0.x, v0.y, v0.z, v0.w, v1.x, v1.y, v1.z, v1.w};
    bf16x8 hv, lv;
#pragma unroll
    for (int j = 0; j < 8; ++j) {
        __bf16 hb = (__bf16)vv[j];
        hv[j] = hb;
        lv[j] = (__bf16)(vv[j] - (float)hb);
    }
    __bf16* o = d + (size_t)row * 3072 + ko * 24;
    if (BSIDE) {
        *(bf16x8*)(o) = hv; *(bf16x8*)(o + 8) = lv; *(bf16x8*)(o + 16) = hv;
    } else {
        *(bf16x8*)(o) = hv; *(bf16x8*)(o + 8) = hv; *(bf16x8*)(o + 16) = lv;
    }
}

// ============ coefficient precompute ============
__global__ void coef_kernel(const float* __restrict__ log_dt,
                            const float* __restrict__ log_A_real,
                            const float* __restrict__ A_imag,
                            const float* __restrict__ C_re,
                            const float* __restrict__ C_im,
                            float* __restrict__ coef) {
    int i = blockIdx.x * blockDim.x + threadIdx.x;
    if (i >= H_DIM * N_ST) return;
    int h = i >> 3;
    float dt = expf(log_dt[h]);
    float Ar = -expf(log_A_real[i]);
    float Ai = A_imag[i];
    float er = expf(dt * Ar);
    float ang = dt * Ai;
    float wr = er * cosf(ang);
    float wi = er * sinf(ang);
    float den = Ar * Ar + Ai * Ai;
    float qr = ((wr - 1.f) * Ar + wi * Ai) / den;
    float qi = (wi * Ar - (wr - 1.f) * Ai) / den;
    float Cr = C_re[i], Ci = C_im[i];
    float Ctr = Cr * qr - Ci * qi;
    float Cti = Cr * qi + Ci * qr;
    float eCL = expf((float)CL * dt * Ar);
    float aCL = (float)CL * dt * Ai;
    float pr = eCL * cosf(aCL);
    float pi = eCL * sinf(aCL);
    const int HN = H_DIM * N_ST;
    coef[i]          = wr;
    coef[HN + i]     = wi;
    coef[2 * HN + i] = Ctr;
    coef[3 * HN + i] = Cti;
    coef[4 * HN + i] = pr;
    coef[5 * HN + i] = pi;
}

// ============ 256x256 fused bf16 GEMM — 4-phase/K-half schedule (round-10/11 WIN) ============
__global__ __launch_bounds__(512, 2) void gemm_f256p(const __bf16* __restrict__ A,
                                                     const __bf16* __restrict__ B,
                                                     float* __restrict__ C,
                                                     int K, int ldc) {
    __shared__ __bf16 sA[32768], sB[32768];
    const int tid = threadIdx.x;
    const int lane = tid & 63;
    const int wid = tid >> 6;
    const int wrw = wid >> 2, wcw = wid & 3;
    const int bm = blockIdx.y, bn = blockIdx.x;

    f32x4 acc[8][4];
#pragma unroll
    for (int m = 0; m < 8; ++m)
#pragma unroll
        for (int n = 0; n < 4; ++n) acc[m][n] = (f32x4){0.f, 0.f, 0.f, 0.f};

    const int kb = lane >> 4, rr = lane & 15;

    const int f0 = tid, f1 = 512 + tid;
    const int kA0 = f0 >> 8, rA0 = f0 & 255;
    const int kA1 = f1 >> 8, rA1 = f1 & 255;
    const size_t gA0 = (size_t)(bm * 256 + rA0) * K;
    const size_t gA1 = (size_t)(bm * 256 + rA1) * K;
    const size_t gB0 = (size_t)(bn * 256 + rA0) * K;
    const size_t gB1 = (size_t)(bn * 256 + rA1) * K;
    const int dst0 = kA0 * 2048 + rA0 * 8;
    const int dst1 = kA1 * 2048 + rA1 * 8;

    auto stageA = [&](int t, int ks) {
        const int base = (t & 1) * 16384 + ks * 8192;
        const size_t go = (size_t)t * 64 + ks * 32;
        gl_lds16(A + gA0 + go + kA0 * 8, &sA[base + dst0]);
        gl_lds16(A + gA1 + go + kA1 * 8, &sA[base + dst1]);
    };
    auto stageB = [&](int t, int ks) {
        const int base = (t & 1) * 16384 + ks * 8192;
        const size_t go = (size_t)t * 64 + ks * 32;
        gl_lds16(B + gB0 + go + kA0 * 8, &sB[base + dst0]);
        gl_lds16(B + gB1 + go + kA1 * 8, &sB[base + dst1]);
    };

    const int nt = K >> 6;   // BK=64
    stageA(0, 0); stageB(0, 0); stageA(0, 1); stageB(0, 1);
    asm volatile("s_waitcnt vmcnt(0)" ::: "memory");
    __builtin_amdgcn_s_barrier();
    __builtin_amdgcn_sched_barrier(0);

#pragma unroll 1
    for (int t = 0; t < nt; ++t) {
        const int par = (t & 1) * 16384;
        const bool pf = (t + 1 < nt);
        bf16x8 fB[4], fA[4];

        // ===== phase 0: (mh=0, ks=0) =====
        {
            const int bA = par, bB = par;
#pragma unroll
            for (int n = 0; n < 4; ++n)
                fB[n] = *(const bf16x8*)&sB[bB + kb * 2048 + (wcw * 64 + n * 16 + rr) * 8];
#pragma unroll
            for (int m = 0; m < 4; ++m)
                fA[m] = *(const bf16x8*)&sA[bA + kb * 2048 + (wrw * 128 + m * 16 + rr) * 8];
            if (pf) stageA(t + 1, 0);
            __builtin_amdgcn_s_barrier();
            asm volatile("s_waitcnt lgkmcnt(0)" ::: "memory");
            __builtin_amdgcn_sched_barrier(0);
            __builtin_amdgcn_s_setprio(1);
#pragma unroll
            for (int m = 0; m < 4; ++m)
#pragma unroll
                for (int n = 0; n < 4; ++n)
                    acc[m][n] = __builtin_amdgcn_mfma_f32_16x16x32_bf16(fA[m], fB[n], acc[m][n], 0, 0, 0);
            __builtin_amdgcn_s_setprio(0);
            __builtin_amdgcn_s_barrier();
            __builtin_amdgcn_sched_barrier(0);
        }
        // ===== phase 1: (mh=1, ks=0)  [gate] =====
        {
            const int bA = par;
#pragma unroll
            for (int m = 0; m < 4; ++m)
                fA[m] = *(const bf16x8*)&sA[bA + kb * 2048 + (wrw * 128 + 64 + m * 16 + rr) * 8];
            if (pf) stageB(t + 1, 0);
            __builtin_amdgcn_s_barrier();
            asm volatile("s_waitcnt lgkmcnt(0)" ::: "memory");
            __builtin_amdgcn_sched_barrier(0);
            __builtin_amdgcn_s_setprio(1);
#pragma unroll
            for (int m = 0; m < 4; ++m)
#pragma unroll
                for (int n = 0; n < 4; ++n)
                    acc[4 + m][n] = __builtin_amdgcn_mfma_f32_16x16x32_bf16(fA[m], fB[n], acc[4 + m][n], 0, 0, 0);
            __builtin_amdgcn_s_setprio(0);
            if (pf) asm volatile("s_waitcnt vmcnt(4)" ::: "memory");
            else    asm volatile("s_waitcnt vmcnt(0)" ::: "memory");
            __builtin_amdgcn_s_barrier();
            __builtin_amdgcn_sched_barrier(0);
        }
        // ===== phase 2: (mh=0, ks=1) =====
        {
            const int bA = par + 8192, bB = par + 8192;
#pragma unroll
            for (int n = 0; n < 4; ++n)
                fB[n] = *(const bf16x8*)&sB[bB + kb * 2048 + (wcw * 64 + n * 16 + rr) * 8];
#pragma unroll
            for (int m = 0; m < 4; ++m)
                fA[m] = *(const bf16x8*)&sA[bA + kb * 2048 + (wrw * 128 + m * 16 + rr) * 8];
            if (pf) stageA(t + 1, 1);
            __builtin_amdgcn_s_barrier();
            asm volatile("s_waitcnt lgkmcnt(0)" ::: "memory");
            __builtin_amdgcn_sched_barrier(0);
            __builtin_amdgcn_s_setprio(1);
#pragma unroll
            for (int m = 0; m < 4; ++m)
#pragma unroll
                for (int n = 0; n < 4; ++n)
                    acc[m][n] = __builtin_amdgcn_mfma_f32_16x16x32_bf16(fA[m], fB[n], acc[m][n], 0, 0, 0);
            __builtin_amdgcn_s_setprio(0);
            __builtin_amdgcn_s_barrier();
            __builtin_amdgcn_sched_barrier(0);
        }
        // ===== phase 3: (mh=1, ks=1)  [gate] =====
        {
            const int bA = par + 8192;
#pragma unroll
            for (int m = 0; m < 4; ++m)
                fA[m] = *(const bf16x8*)&sA[bA + kb * 2048 + (wrw * 128 + 64 + m * 16 + rr) * 8];
            if (pf) stageB(t + 1, 1);
            __builtin_amdgcn_s_barrier();
            asm volatile("s_waitcnt lgkmcnt(0)" ::: "memory");
            __builtin_amdgcn_sched_barrier(0);
            __builtin_amdgcn_s_setprio(1);
#pragma unroll
            for (int m = 0; m < 4; ++m)
#pragma unroll
                for (int n = 0; n < 4; ++n)
                    acc[4 + m][n] = __builtin_amdgcn_mfma_f32_16x16x32_bf16(fA[m], fB[n], acc[4 + m][n], 0, 0, 0);
            __builtin_amdgcn_s_setprio(0);
            if (pf) asm volatile("s_waitcnt vmcnt(4)" ::: "memory");
            else    asm volatile("s_waitcnt vmcnt(0)" ::: "memory");
            __builtin_amdgcn_s_barrier();
            __builtin_amdgcn_sched_barrier(0);
        }
    }

    const int rq = lane >> 4;
#pragma unroll
    for (int m = 0; m < 8; ++m)
#pragma unroll
        for (int n = 0; n < 4; ++n) {
            int col = bn * 256 + wcw * 64 + n * 16 + rr;
            int row0 = bm * 256 + wrw * 128 + m * 16 + rq * 4;
#pragma unroll
            for (int j = 0; j < 4; ++j)
                C[(size_t)(row0 + j) * ldc + col] = acc[m][n][j];
        }
}

// ============ 128x128 split-plane out-GEMM — 512 threads / 8 waves (round-15 WIN) ============
__global__ __launch_bounds__(512, 1) void gemm_s128w(const __bf16* __restrict__ Ah,
                                                     const __bf16* __restrict__ Al,
                                                     const __bf16* __restrict__ Bh,
                                                     const __bf16* __restrict__ Bl,
                                                     float* __restrict__ C,
                                                     int K, int ldc) {
    __shared__ __bf16 sAh[2][2][4096], sAl[2][2][4096];
    __shared__ __bf16 sBh[2][2][4096], sBl[2][2][4096];
    const int tid = threadIdx.x;
    const int lane = tid & 63;
    const int wid = tid >> 6;
    const int wrw = wid >> 2;
    const int wcw = wid & 3;
    const int bm = blockIdx.y, bn = blockIdx.x;

    f32x4 acc[4][2];
#pragma unroll
    for (int m = 0; m < 4; ++m)
#pragma unroll
        for (int n = 0; n < 2; ++n) acc[m][n] = (f32x4){0.f, 0.f, 0.f, 0.f};

    const int kb = lane >> 4, rr = lane & 15;

    const int kbs = tid >> 7, rw = tid & 127;
    const size_t gAr = (size_t)(bm * 128 + rw) * K;
    const size_t gBr = (size_t)(bn * 128 + rw) * K;
    const int dd = kbs * 1024 + rw * 8;

    auto stA = [&](int t, int ks) {
        const int par = t & 1;
        const size_t go = (size_t)t * 64 + ks * 32 + kbs * 8;
        gl_lds16(Ah + gAr + go, &sAh[par][ks][dd]);
        gl_lds16(Al + gAr + go, &sAl[par][ks][dd]);
    };
    auto stB = [&](int t, int ks) {
        const int par = t & 1;
        const size_t go = (size_t)t * 64 + ks * 32 + kbs * 8;
        gl_lds16(Bh + gBr + go, &sBh[par][ks][dd]);
        gl_lds16(Bl + gBr + go, &sBl[par][ks][dd]);
    };

    const int nt = K >> 6;   // BK=64
    stA(0, 0); stB(0, 0); stA(0, 1); stB(0, 1);
    asm volatile("s_waitcnt vmcnt(0)" ::: "memory");
    __builtin_amdgcn_s_barrier();
    __builtin_amdgcn_sched_barrier(0);

    bf16x8 fAh[4], fAl[4], fBh[2], fBl[2];

#pragma unroll 1
    for (int t = 0; t < nt; ++t) {
        const int par = t & 1;
        const bool pf = (t + 1 < nt);

        // ===== phase 0 (ks=0) =====
        {
#pragma unroll
            for (int n = 0; n < 2; ++n) {
                const int off = kb * 1024 + (wcw * 32 + n * 16 + rr) * 8;
                fBh[n] = *(const bf16x8*)&sBh[par][0][off];
                fBl[n] = *(const bf16x8*)&sBl[par][0][off];
            }
#pragma unroll
            for (int m = 0; m < 4; ++m) {
                const int off = kb * 1024 + (wrw * 64 + m * 16 + rr) * 8;
                fAh[m] = *(const bf16x8*)&sAh[par][0][off];
                fAl[m] = *(const bf16x8*)&sAl[par][0][off];
            }
            if (pf) stA(t + 1, 0);
            __builtin_amdgcn_s_barrier();
            asm volatile("s_waitcnt lgkmcnt(0)" ::: "memory");
            __builtin_amdgcn_sched_barrier(0);
            __builtin_amdgcn_s_setprio(1);
#pragma unroll
            for (int m = 0; m < 2; ++m)
#pragma unroll
                for (int n = 0; n < 2; ++n) {
                    acc[m][n] = __builtin_amdgcn_mfma_f32_16x16x32_bf16(fAh[m], fBh[n], acc[m][n], 0, 0, 0);
                    acc[m][n] = __builtin_amdgcn_mfma_f32_16x16x32_bf16(fAh[m], fBl[n], acc[m][n], 0, 0, 0);
                    acc[m][n] = __builtin_amdgcn_mfma_f32_16x16x32_bf16(fAl[m], fBh[n], acc[m][n], 0, 0, 0);
                }
            __builtin_amdgcn_s_setprio(0);
            __builtin_amdgcn_s_barrier();
            __builtin_amdgcn_sched_barrier(0);
        }
        // ===== phase 1 (ks=0) [gate] =====
        {
            if (pf) stB(t + 1, 0);
            __builtin_amdgcn_s_barrier();
            __builtin_amdgcn_sched_barrier(0);
            __builtin_amdgcn_s_setprio(1);
#pragma unroll
            for (int m = 2; m < 4; ++m)
#pragma unroll
                for (int n = 0; n < 2; ++n) {
                    acc[m][n] = __builtin_amdgcn_mfma_f32_16x16x32_bf16(fAh[m], fBh[n], acc[m][n], 0, 0, 0);
                    acc[m][n] = __builtin_amdgcn_mfma_f32_16x16x32_bf16(fAh[m], fBl[n], acc[m][n], 0, 0, 0);
                    acc[m][n] = __builtin_amdgcn_mfma_f32_16x16x32_bf16(fAl[m], fBh[n], acc[m][n], 0, 0, 0);
                }
            __builtin_amdgcn_s_setprio(0);
            if (pf) asm volatile("s_waitcnt vmcnt(4)" ::: "memory");
            else    asm volatile("s_waitcnt vmcnt(0)" ::: "memory");
            __builtin_amdgcn_s_barrier();
            __builtin_amdgcn_sched_barrier(0);
        }
        // ===== phase 2 (ks=1) =====
        {
#pragma unroll
            for (int n = 0; n < 2; ++n) {
                const int off = kb * 1024 + (wcw * 32 + n * 16 + rr) * 8;
                fBh[n] = *(const bf16x8*)&sBh[par][1][off];
                fBl[n] = *(const bf16x8*)&sBl[par][1][off];
            }
#pragma unroll
            for (int m = 0; m < 4; ++m) {
                const int off = kb * 1024 + (wrw * 64 + m * 16 + rr) * 8;
                fAh[m] = *(const bf16x8*)&sAh[par][1][off];
                fAl[m] = *(const bf16x8*)&sAl[par][1][off];
            }
            if (pf) stA(t + 1, 1);
            __builtin_amdgcn_s_barrier();
            asm volatile("s_waitcnt lgkmcnt(0)" ::: "memory");
            __builtin_amdgcn_sched_barrier(0);
            __builtin_amdgcn_s_setprio(1);
#pragma unroll
            for (int m = 0; m < 2; ++m)
#pragma unroll
                for (int n = 0; n < 2; ++n) {
                    acc[m][n] = __builtin_amdgcn_mfma_f32_16x16x32_bf16(fAh[m], fBh[n], acc[m][n], 0, 0, 0);
                    acc[m][n] = __builtin_amdgcn_mfma_f32_16x16x32_bf16(fAh[m], fBl[n], acc[m][n], 0, 0, 0);
                    acc[m][n] = __builtin_amdgcn_mfma_f32_16x16x32_bf16(fAl[m], fBh[n], acc[m][n], 0, 0, 0);
                }
            __builtin_amdgcn_s_setprio(0);
            __builtin_amdgcn_s_barrier();
            __builtin_amdgcn_sched_barrier(0);
        }
        // ===== phase 3 (ks=1) [gate] =====
        {
            if (pf) stB(t + 1, 1);
            __builtin_amdgcn_s_barrier();
            __builtin_amdgcn_sched_barrier(0);
            __builtin_amdgcn_s_setprio(1);
#pragma unroll
            for (int m = 2; m < 4; ++m)
#pragma unroll
                for (int n = 0; n < 2; ++n) {
                    acc[m][n] = __builtin_amdgcn_mfma_f32_16x16x32_bf16(fAh[m], fBh[n], acc[m][n], 0, 0, 0);
                    acc[m][n] = __builtin_amdgcn_mfma_f32_16x16x32_bf16(fAh[m], fBl[n], acc[m][n], 0, 0, 0);
                    acc[m][n] = __builtin_amdgcn_mfma_f32_16x16x32_bf16(fAl[m], fBh[n], acc[m][n], 0, 0, 0);
                }
            __builtin_amdgcn_s_setprio(0);
            if (pf) asm volatile("s_waitcnt vmcnt(4)" ::: "memory");
            else    asm volatile("s_waitcnt vmcnt(0)" ::: "memory");
            __builtin_amdgcn_s_barrier();
            __builtin_amdgcn_sched_barrier(0);
        }
    }

    const int rq = lane >> 4;
#pragma unroll
    for (int m = 0; m < 4; ++m)
#pragma unroll
        for (int n = 0; n < 2; ++n) {
            int col = bn * 128 + wcw * 32 + n * 16 + rr;
            int row0 = bm * 128 + wrw * 64 + m * 16 + rq * 4;
#pragma unroll
            for (int j = 0; j < 4; ++j)
                C[(size_t)(row0 + j) * ldc + col] = acc[m][n][j];
        }
}

// ============ scan phase 1: local chunk scans (fused conv+SiLU) ============
__global__ __launch_bounds__(256) void scan_phase1(const float* __restrict__ xz,
                                                   const float* __restrict__ coef,
                                                   const float* __restrict__ conv_w,
                                                   const float* __restrict__ conv_b,
                                                   float* __restrict__ states) {
    int t = blockIdx.x * 256 + threadIdx.x;   // t = h*NC + c
    int c = t & (NC - 1);
    int h = t >> 5;

    const int HN = H_DIM * N_ST;
    float wr[N_ST], wi[N_ST];
#pragma unroll
    for (int n = 0; n < N_ST; ++n) {
        wr[n] = coef[h * N_ST + n];
        wi[n] = coef[HN + h * N_ST + n];
    }
    float cw0 = conv_w[h * 4 + 0], cw1 = conv_w[h * 4 + 1];
    float cw2 = conv_w[h * 4 + 2], cw3 = conv_w[h * 4 + 3];
    float cb = conv_b[h];

    const float* xrow = xz + (size_t)h * L_SEQ + c * CL;
    float x3 = 0.f, x2 = 0.f, x1 = 0.f;
    if (c > 0) {
        float4 p = *(const float4*)(xrow - 4);
        x3 = p.y; x2 = p.z; x1 = p.w;
    }

    float sr[N_ST], si[N_ST];
#pragma unroll
    for (int n = 0; n < N_ST; ++n) { sr[n] = 0.f; si[n] = 0.f; }

    for (int j = 0; j < CL; j += 4) {
        float4 v = *(const float4*)(xrow + j);
        float xv[4] = {v.x, v.y, v.z, v.w};
#pragma unroll
        for (int k = 0; k < 4; ++k) {
            float u = cw0 * x3 + cw1 * x2 + cw2 * x1 + cw3 * xv[k] + cb;
            float xc = u / (1.f + __expf(-u));
            x3 = x2; x2 = x1; x1 = xv[k];
#pragma unroll
            for (int n = 0; n < N_ST; ++n) {
                float nr = wr[n] * sr[n] - wi[n] * si[n] + xc;
                float ni = wr[n] * si[n] + wi[n] * sr[n];
                sr[n] = nr; si[n] = ni;
            }
        }
    }
    float* st = states + (size_t)t * (N_ST * 2);
#pragma unroll
    for (int n = 0; n < N_ST; ++n) { st[2 * n] = sr[n]; st[2 * n + 1] = si[n]; }
}

// ============ scan phase 2: combine chunk states -> chunk init states ============
__global__ __launch_bounds__(256) void scan_phase2(const float* __restrict__ coef,
                                                   float* __restrict__ states) {
    int h = blockIdx.x * 256 + threadIdx.x;
    if (h >= H_DIM) return;
    const int HN = H_DIM * N_ST;
    float pr[N_ST], pi[N_ST];
#pragma unroll
    for (int n = 0; n < N_ST; ++n) {
        pr[n] = coef[4 * HN + h * N_ST + n];
        pi[n] = coef[5 * HN + h * N_ST + n];
    }
    float sr[N_ST], si[N_ST];
#pragma unroll
    for (int n = 0; n < N_ST; ++n) { sr[n] = 0.f; si[n] = 0.f; }
    float* base = states + (size_t)h * NC * (N_ST * 2);
    for (int c = 0; c < NC; ++c) {
        float* st = base + c * (N_ST * 2);
#pragma unroll
        for (int n = 0; n < N_ST; ++n) {
            float lr = st[2 * n], li = st[2 * n + 1];
            st[2 * n] = sr[n]; st[2 * n + 1] = si[n];
            float nr = pr[n] * sr[n] - pi[n] * si[n] + lr;
            float ni = pr[n] * si[n] + pi[n] * sr[n] + li;
            sr[n] = nr; si[n] = ni;
        }
    }
}

// ============ scan phase 3 + transpose + split fused ============
__global__ __launch_bounds__(256) void scan_phase3t(const float* __restrict__ xz,
                                                    const float* __restrict__ coef,
                                                    const float* __restrict__ conv_w,
                                                    const float* __restrict__ conv_b,
                                                    const float* __restrict__ Dvec,
                                                    const float* __restrict__ states,
                                                    __bf16* __restrict__ th,
                                                    __bf16* __restrict__ tl) {
    const int lane = threadIdx.x & 63;
    const int wv = threadIdx.x >> 6;             // 0..3
    const int c = blockIdx.x * 4 + wv;           // chunk 0..31
    const int h = blockIdx.y * 64 + lane;        // 0..2047
    const int t = h * NC + c;

    const int HN = H_DIM * N_ST;
    float wr[N_ST], wi[N_ST], Ctr[N_ST], Cti[N_ST];
#pragma unroll
    for (int n = 0; n < N_ST; ++n) {
        wr[n]  = coef[h * N_ST + n];
        wi[n]  = coef[HN + h * N_ST + n];
        Ctr[n] = coef[2 * HN + h * N_ST + n];
        Cti[n] = coef[3 * HN + h * N_ST + n];
    }
    float cw0 = conv_w[h * 4 + 0], cw1 = conv_w[h * 4 + 1];
    float cw2 = conv_w[h * 4 + 2], cw3 = conv_w[h * 4 + 3];
    float cb = conv_b[h];
    float Dh = Dvec[h];

    const float* xrow = xz + (size_t)h * L_SEQ + c * CL;
    const float* zrow = xz + (size_t)(H_DIM + h) * L_SEQ + c * CL;

    float x3 = 0.f, x2 = 0.f, x1 = 0.f;
    if (c > 0) {
        float4 p = *(const float4*)(xrow - 4);
        x3 = p.y; x2 = p.z; x1 = p.w;
    }

    const float* st = states + (size_t)t * (N_ST * 2);
    float sr[N_ST], si[N_ST];
#pragma unroll
    for (int n = 0; n < N_ST; ++n) { sr[n] = st[2 * n]; si[n] = st[2 * n + 1]; }

    __bf16* thp = th + (size_t)(c * CL) * H_DIM + h;
    __bf16* tlp = tl + (size_t)(c * CL) * H_DIM + h;

    for (int j = 0; j < CL; j += 4) {
        float4 v = *(const float4*)(xrow + j);
        float4 zv = *(const float4*)(zrow + j);
        float xv[4] = {v.x, v.y, v.z, v.w};
        float zz[4] = {zv.x, zv.y, zv.z, zv.w};
#pragma unroll
        for (int k = 0; k < 4; ++k) {
            float u = cw0 * x3 + cw1 * x2 + cw2 * x1 + cw3 * xv[k] + cb;
            float xc = u / (1.f + __expf(-u));
            x3 = x2; x2 = x1; x1 = xv[k];
            float accy = 0.f;
#pragma unroll
            for (int n = 0; n < N_ST; ++n) {
                float nr = wr[n] * sr[n] - wi[n] * si[n] + xc;
                float ni = wr[n] * si[n] + wi[n] * sr[n];
                sr[n] = nr; si[n] = ni;
                accy += Ctr[n] * nr - Cti[n] * ni;
            }
            float yv = 2.f * accy + Dh * xc;
            float g = zz[k] / (1.f + __expf(-zz[k]));
            float val = yv * g;
            __bf16 hb = (__bf16)val;
            __bf16 lb = (__bf16)(val - (float)hb);
            thp[(size_t)(j + k) * H_DIM] = hb;
            tlp[(size_t)(j + k) * H_DIM] = lb;
        }
    }
}

extern "C" void kernel_launch(void* const* d_in, const int* in_sizes, int n_in,
                              void* d_out, int out_size, void* d_ws, size_t ws_size,
                              hipStream_t stream) {
    const float* hid        = (const float*)d_in[0];
    const float* W_in       = (const float*)d_in[1];
    const float* conv_w     = (const float*)d_in[2];
    const float* conv_b     = (const float*)d_in[3];
    const float* log_dt     = (const float*)d_in[4];
    const float* log_A_real = (const float*)d_in[5];
    const float* A_imag     = (const float*)d_in[6];
    const float* C_re       = (const float*)d_in[7];
    const float* C_im       = (const float*)d_in[8];
    const float* Dv         = (const float*)d_in[9];
    const float* W_out      = (const float*)d_in[10];
    float* out = (float*)d_out;
    float* ws  = (float*)d_ws;

    float* xz      = ws + WS_XZ;
    float* coef    = ws + WS_COEF;
    float* states  = ws + WS_STATES;
    __bf16* Hf     = (__bf16*)(ws + WS_HF);
    __bf16* WiF    = (__bf16*)(ws + WS_WIF);
    __bf16* Woh    = (__bf16*)(ws + WS_WOH);
    __bf16* Wol    = (__bf16*)(ws + WS_WOL);
    __bf16* yTh    = (__bf16*)(ws + WS_HF);    // overlays Hf (dead at phase3t time)
    __bf16* yTl    = (__bf16*)(ws + WS_YTL);

    coef_kernel<<<(H_DIM * N_ST + 255) / 256, 256, 0, stream>>>(
        log_dt, log_A_real, A_imag, C_re, C_im, coef);

    const int wOct = 2 * H_DIM * DMODEL / 8;   // 524288
    cvt_fuse<0><<<(wOct + 255) / 256, 256, 0, stream>>>(W_in, WiF, wOct);
    cvt_split4<<<(DMODEL * H_DIM / 4 + 255) / 256, 256, 0, stream>>>(W_out, Woh, Wol, DMODEL * H_DIM / 4);

    const int nscan = H_DIM * NC;              // 65536
    const int hOct = L_SEQ * DMODEL / 8;       // 524288
    dim3 gIn(L_SEQ / 256, 2 * H_DIM / 256);    // (16,16) = 256 blocks
    dim3 gOut(DMODEL / 128, L_SEQ / 128);      // (8,32)  = 256 blocks
    dim3 gP3(NC / 4, H_DIM / 64);              // (8,32)  = 256 blocks

    for (int b = 0; b < B_SZ; ++b) {
        const float* hid_b = hid + (size_t)b * L_SEQ * DMODEL;
        float* out_b = out + (size_t)b * L_SEQ * DMODEL;

        cvt_fuse<1><<<(hOct + 255) / 256, 256, 0, stream>>>(hid_b, Hf, hOct);
        gemm_f256p<<<gIn, 512, 0, stream>>>(WiF, Hf, xz, 3 * DMODEL, L_SEQ);
        scan_phase1<<<nscan / 256, 256, 0, stream>>>(xz, coef, conv_w, conv_b, states);
        scan_phase2<<<(H_DIM + 255) / 256, 256, 0, stream>>>(coef, states);
        scan_phase3t<<<gP3, 256, 0, stream>>>(xz, coef, conv_w, conv_b, Dv, states, yTh, yTl);
        gemm_s128w<<<gOut, 512, 0, stream>>>(yTh, yTl, Woh, Wol, out_b, H_DIM, DMODEL);
    }
}